// Round 18
// baseline (102.391 us; speedup 1.0000x reference)
//
#include <hip/hip_runtime.h>

// Packed-sequence LSTM (B=4096, T=512, D=18, H=8) + Linear(8->1) head.
//
// R18 = R14 (best 75.9us) with the window extended 16->32 steps and rings
// enlarged so LDS = 58KB -> 2 blocks/CU -> 4 waves on 4 SIMDs = 1 wave/SIMD.
// Model (from R11/R13/R17 nulls + R12/R14 wins): wall = consumer chain +
// rendezvous + SIMD-sharing tax; instruction count is NOT binding. This
// change halves rendezvous count AND removes wave sharing while keeping the
// proven 16-lane DPP consumer (R16's 8-lane shfl variant is the disease to
// avoid: ds_bpermute on the serial chain).
//
// Producer iter I: DMA chunks {4I+8..4I+11} (36 ops), vmcnt(36) retires
// {4I+4..4I+7} (issued one iter ~10kcy ago >> 900cy HBM; producer wave has
// NO stores -> counts exact), produce {4I+4..4I+7}, lgkm(0), s_barrier.
// Prologue: DMA {0..7} (72 ops), vmcnt(36) -> {0..3} ready, produce, bar.
// Ring disjointness (re-derived): Aring mod-64: DMA rows (32I+64..95)&63
// vs produce reads (32I+32..63)&63 = complementary 32-row halves, both
// parities. Bring mod-8: writes (4I+8..11)&7 vs reads (4I+4..7)&7 disjoint.
// XG mod-8: writes {4I+4..7}&7 vs consumer reads {4I..4I+3}&7 disjoint.
// Consumer window I: first xg read AFTER the barrier (writer ran last
// iter, lgkm-drained); in-window prefetch 1 step ahead, stops at k=31;
// y stored in two 16-step groups (k==15, k==31) to cap VGPRs.

namespace {

constexpr int NT = 512;
constexpr int ND = 18;
constexpr float LOG2E = 1.4426950408889634f;

typedef float v2f __attribute__((ext_vector_type(2)));
typedef float v4f __attribute__((ext_vector_type(4)));

template <int C>
__device__ __forceinline__ float fdpp(float v) {
    const int i = __float_as_int(v);
    return __int_as_float(__builtin_amdgcn_update_dpp(i, i, C, 0xF, 0xF, true));
}
__device__ __forceinline__ void gload_lds(const void* g, void* l) {
    __builtin_amdgcn_global_load_lds(
        (const __attribute__((address_space(1))) void*)g,
        (__attribute__((address_space(3))) void*)l, 4, 0, 0);
}

__global__ __launch_bounds__(128, 1) void lstm_pc(
    const float* __restrict__ x, const int* __restrict__ lengths,
    const float* __restrict__ W_ih, const float* __restrict__ W_hh,
    const float* __restrict__ b_ih, const float* __restrict__ b_hh,
    const float* __restrict__ W_lin, const float* __restrict__ b_lin,
    float* __restrict__ out)
{
    // Aring: 64 row slots (row r -> slot r&63), [seq][elem0..15].   16KB
    // Bring: 8 chunk bufs, [row-in-chunk][seq][elem16..17].          2KB
    // XG:    8 chunk bufs, [step][gate-pair][seq(+1 pad)] of v2f.   40KB
    __shared__ __align__(16) float Aring[64][4][16];
    __shared__ __align__(16) float Bring[8][8][4][2];
    __shared__ __align__(16) v2f   XG[8][8][16][5];

    // Length-balanced swizzle (R14-proven): round-slot q hosts groups
    // {q, 1023-q, 256+q, 767-q} -> per-CU work ~constant.
    const int q_ = (int)blockIdx.x & 255;
    const int r_ = (int)blockIdx.x >> 8;
    const int g  = (r_ == 0) ? q_ : (r_ == 1) ? (1023 - q_)
                 : (r_ == 2) ? (256 + q_) : (767 - q_);

    const int tid  = (int)threadIdx.x;
    const int wav  = tid >> 6;          // 0 = consumer, 1 = producer
    const int w    = tid & 63;
    const int grp  = w >> 4;            // seq within block
    const int l16  = w & 15;
    const int p    = l16 >> 3;          // half: 0 -> {i,g}, 1 -> {f,o}
    const int j    = l16 & 7;           // hidden unit
    const int lenmax = lengths[g * 4];  // sorted desc -> block max
    const int nwin = (lenmax + 31) >> 5;              // 32-step windows
    const int rowA = j + (p ? 8 : 0);   // p0: i, p1: f
    const int rowB = j + (p ? 24 : 16); // p0: g, p1: o

    if (wav == 1) {
        // ============================ PRODUCER ============================
        v2f wxA[9], wxB[9];
        {
            const v2f* ra = (const v2f*)(W_ih + rowA * ND);
            const v2f* rb = (const v2f*)(W_ih + rowB * ND);
#pragma unroll
            for (int k = 0; k < 9; ++k) { wxA[k] = ra[k]; wxB[k] = rb[k]; }
        }
        const float biasA = b_ih[rowA] + b_hh[rowA];
        const float biasB = b_ih[rowB] + b_hh[rowB];

        // DMA source lanes: A-op: seq w>>4, elem w&15 (row uniform).
        // B-op: row w>>3, seq (w>>1)&3, elem 16+(w&1); dest linear = lane.
        const char* xc = (const char*)x;
        const char* pA = xc + (size_t)((((unsigned)(g * 4 + (w >> 4)) * (NT * ND))
                                       + (unsigned)(w & 15)) * 4u);
        const char* pB = xc + (size_t)((((unsigned)(g * 4 + ((w >> 1) & 3)) * (NT * ND))
                                       + 16u + (unsigned)(w & 1)) * 4u);
        const unsigned rB0 = (unsigned)(w >> 3);

        auto dma_chunk = [&](int dd) {            // 9 vmem ops
            const int r0 = dd * 8;
#pragma unroll
            for (int k = 0; k < 8; ++k) {
                const int rr = (r0 + k < NT) ? (r0 + k) : (NT - 1);
                gload_lds(pA + (unsigned)rr * 72u, &Aring[(r0 + k) & 63][0][0]);
            }
            unsigned rb = (unsigned)r0 + rB0;
            rb = (rb < (unsigned)NT) ? rb : (unsigned)(NT - 1);
            gload_lds(pB + rb * 72u, &Bring[dd & 7][0][0][0]);
        };

        // plain compiler-scheduled produce (R9/R11/R13/R17: don't hand-tune)
        auto produce_chunk = [&](int cc) {
            const int s0 = (cc * 8) & 63;
            const int bf = cc & 7;
#pragma unroll
            for (int k = 0; k < 8; ++k) {
                const v4f* ap = (const v4f*)&Aring[s0 + k][grp][0];
                const v4f q0 = ap[0], q1 = ap[1], q2 = ap[2], q3 = ap[3];
                const v2f bt = *(const v2f*)&Bring[bf][k][grp][0];
                v2f aA = v2f{biasA, 0.f}, aB = v2f{biasB, 0.f};
                aA = q0.lo * wxA[0] + aA;  aB = q0.lo * wxB[0] + aB;
                aA = q0.hi * wxA[1] + aA;  aB = q0.hi * wxB[1] + aB;
                aA = q1.lo * wxA[2] + aA;  aB = q1.lo * wxB[2] + aB;
                aA = q1.hi * wxA[3] + aA;  aB = q1.hi * wxB[3] + aB;
                aA = q2.lo * wxA[4] + aA;  aB = q2.lo * wxB[4] + aB;
                aA = q2.hi * wxA[5] + aA;  aB = q2.hi * wxB[5] + aB;
                aA = q3.lo * wxA[6] + aA;  aB = q3.lo * wxB[6] + aB;
                aA = q3.hi * wxA[7] + aA;  aB = q3.hi * wxB[7] + aB;
                aA = bt * wxA[8] + aA;     aB = bt * wxB[8] + aB;
                XG[bf][k][l16][grp] = v2f{aA.x + aA.y, aB.x + aB.y};
            }
        };

        // prologue: DMA chunks 0..7 (72 ops); vmcnt(36) -> {0..3} ready
        dma_chunk(0); dma_chunk(1); dma_chunk(2); dma_chunk(3);
        dma_chunk(4); dma_chunk(5); dma_chunk(6); dma_chunk(7);
        asm volatile("s_waitcnt vmcnt(36)" ::: "memory");
        produce_chunk(0); produce_chunk(1); produce_chunk(2); produce_chunk(3);
        asm volatile("s_waitcnt lgkmcnt(0)" ::: "memory");
        __builtin_amdgcn_sched_barrier(0);
        __builtin_amdgcn_s_barrier();
        __builtin_amdgcn_sched_barrier(0);

        for (int I = 0; I < nwin; ++I) {
            dma_chunk(4 * I + 8);
            dma_chunk(4 * I + 9);
            dma_chunk(4 * I + 10);
            dma_chunk(4 * I + 11);
            asm volatile("s_waitcnt vmcnt(36)" ::: "memory");
            produce_chunk(4 * I + 4);
            produce_chunk(4 * I + 5);
            produce_chunk(4 * I + 6);
            produce_chunk(4 * I + 7);
            asm volatile("s_waitcnt lgkmcnt(0)" ::: "memory");
            __builtin_amdgcn_sched_barrier(0);
            __builtin_amdgcn_s_barrier();
            __builtin_amdgcn_sched_barrier(0);
        }
    } else {
        // ============================ CONSUMER ============================
        const int len = lengths[g * 4 + grp];

        // DPP self-calibration: which h-index does row_ror:r deliver here?
        int idx[8];
        idx[0] = j;
        idx[1] = __builtin_amdgcn_update_dpp(0, j, 0x121, 0xF, 0xF, true) & 7;
        idx[2] = __builtin_amdgcn_update_dpp(0, j, 0x122, 0xF, 0xF, true) & 7;
        idx[3] = __builtin_amdgcn_update_dpp(0, j, 0x123, 0xF, 0xF, true) & 7;
        idx[4] = __builtin_amdgcn_update_dpp(0, j, 0x124, 0xF, 0xF, true) & 7;
        idx[5] = __builtin_amdgcn_update_dpp(0, j, 0x125, 0xF, 0xF, true) & 7;
        idx[6] = __builtin_amdgcn_update_dpp(0, j, 0x126, 0xF, 0xF, true) & 7;
        idx[7] = __builtin_amdgcn_update_dpp(0, j, 0x127, 0xF, 0xF, true) & 7;

        v2f whA[4], whB[4], wl2[4];
#pragma unroll
        for (int r = 0; r < 4; ++r) {
            whA[r] = v2f{W_hh[rowA * 8 + idx[2 * r]], W_hh[rowA * 8 + idx[2 * r + 1]]};
            whB[r] = v2f{W_hh[rowB * 8 + idx[2 * r]], W_hh[rowB * 8 + idx[2 * r + 1]]};
            wl2[r] = v2f{W_lin[idx[2 * r]], W_lin[idx[2 * r + 1]]};
        }
        const float bl = b_lin[0];
        // vB exponent scale: p0 computes tanh(g)=2*sigma(2g)-1, p1 sigma(o)
        const float Kp = p ? -LOG2E : -2.0f * LOG2E;

        float* yb = out + (size_t)(g * 4 + grp) * NT;

        v2f hp[4] = {v2f{0.f, 0.f}, v2f{0.f, 0.f}, v2f{0.f, 0.f}, v2f{0.f, 0.f}};
        float c_ = 0.0f, hown = 0.0f;

        __builtin_amdgcn_s_barrier();           // pairs with producer prologue
        __builtin_amdgcn_sched_barrier(0);

        for (int I = 0; I < nwin; ++I) {
            const int t = I * 32;
            // chunk pointers for this window (step stride = 80 v2f)
            const v2f* xgc0 = &XG[(4 * I)     & 7][0][l16][grp];
            const v2f* xgc1 = &XG[(4 * I + 1) & 7][0][l16][grp];
            const v2f* xgc2 = &XG[(4 * I + 2) & 7][0][l16][grp];
            const v2f* xgc3 = &XG[(4 * I + 3) & 7][0][l16][grp];
            float y[16];
            v2f xgn = xgc0[0];  // first read AFTER barrier (writer last iter)
#pragma unroll
            for (int k = 0; k < 32; ++k) {
                const v2f xgc = xgn;
                if (k < 31) {
                    const int kn = k + 1;
                    xgn = (kn < 8)  ? xgc0[kn * 80]
                        : (kn < 16) ? xgc1[(kn - 8) * 80]
                        : (kn < 24) ? xgc2[(kn - 16) * 80]
                                    : xgc3[(kn - 24) * 80];
                }

                // recurrent dots
                v2f tA = hp[0] * whA[0];
                tA = hp[1] * whA[1] + tA;
                tA = hp[2] * whA[2] + tA;
                tA = hp[3] * whA[3] + tA;
                v2f tB = hp[0] * whB[0];
                tB = hp[1] * whB[1] + tB;
                tB = hp[2] * whB[2] + tB;
                tB = hp[3] * whB[3] + tB;
                const float aA = (xgc.x + tA.x) + tA.y;
                const float aB = (xgc.y + tB.x) + tB.y;

                // activations: vA = sigma(i|f); vB = p0 tanh(g), p1 sigma(o)
                const float vA = __builtin_amdgcn_rcpf(
                    1.0f + __builtin_amdgcn_exp2f(aA * -LOG2E));
                const float sB = __builtin_amdgcn_rcpf(
                    1.0f + __builtin_amdgcn_exp2f(aB * Kp));
                const float vB = p ? sB : fmaf(2.0f, sB, -1.0f);

                // half exchange via ror:8; unmasked cell update
                const float send1 = p ? vA : (vA * vB);
                const float ex1 = fdpp<0x128>(send1);
                const float f_ = p ? send1 : ex1;
                const float ig_ = p ? ex1 : send1;
                c_ = fmaf(f_, c_, ig_);
                const float tc = fmaf(-2.0f, __builtin_amdgcn_rcpf(
                    1.0f + __builtin_amdgcn_exp2f(c_ * (2.0f * LOG2E))), 1.0f);
                const float ex2 = fdpp<0x128>(vB);
                const float o_ = p ? vB : ex2;
                hown = o_ * tc;

                // h rotations -> pairs
                const float h1 = fdpp<0x121>(hown);
                const float h2 = fdpp<0x122>(hown);
                const float h3 = fdpp<0x123>(hown);
                const float h4 = fdpp<0x124>(hown);
                const float h5 = fdpp<0x125>(hown);
                const float h6 = fdpp<0x126>(hown);
                const float h7 = fdpp<0x127>(hown);
                hp[0] = v2f{hown, h1}; hp[1] = v2f{h2, h3};
                hp[2] = v2f{h4, h5};   hp[3] = v2f{h6, h7};

                // linear head (off the critical chain)
                v2f ya = hp[0] * wl2[0];
                ya = hp[1] * wl2[1] + ya;
                ya = hp[2] * wl2[2] + ya;
                ya = hp[3] * wl2[3] + ya;
                y[k & 15] = (ya.x + ya.y) + bl;

                // flush y in 16-step groups (caps VGPR use)
                if (k == 15 || k == 31) {
                    const int tb = t + (k & 16);
                    if (l16 == 0) {
                        if (tb + 15 < len) {
                            *(v4f*)(yb + tb)      = v4f{y[0],  y[1],  y[2],  y[3]};
                            *(v4f*)(yb + tb + 4)  = v4f{y[4],  y[5],  y[6],  y[7]};
                            *(v4f*)(yb + tb + 8)  = v4f{y[8],  y[9],  y[10], y[11]};
                            *(v4f*)(yb + tb + 12) = v4f{y[12], y[13], y[14], y[15]};
                        } else {
#pragma unroll
                            for (int kk = 0; kk < 16; ++kk)
                                if (tb + kk < len) yb[tb + kk] = y[kk];
                        }
                    }
                }
            }

            __builtin_amdgcn_sched_barrier(0);
            __builtin_amdgcn_s_barrier();
            __builtin_amdgcn_sched_barrier(0);
        }
    }
}

} // namespace

extern "C" void kernel_launch(void* const* d_in, const int* in_sizes, int n_in,
                              void* d_out, int out_size, void* d_ws, size_t ws_size,
                              hipStream_t stream) {
    const float* x     = (const float*)d_in[0];
    const int*   lens  = (const int*)d_in[1];
    const float* W_ih  = (const float*)d_in[2];
    const float* W_hh  = (const float*)d_in[3];
    const float* b_ih  = (const float*)d_in[4];
    const float* b_hh  = (const float*)d_in[5];
    const float* W_lin = (const float*)d_in[6];
    const float* b_lin = (const float*)d_in[7];
    float* out = (float*)d_out;

    // zero the padded region (kernel only writes t < len)
    hipMemsetAsync(out, 0, (size_t)4096 * NT * sizeof(float), stream);

    lstm_pc<<<1024, 128, 0, stream>>>(x, lens, W_ih, W_hh, b_ih, b_hh,
                                      W_lin, b_lin, out);
}

// Round 20
// 80.568 us; speedup vs baseline: 1.2709x; 1.2709x over previous
//
#include <hip/hip_runtime.h>

// Packed-sequence LSTM (B=4096, T=512, D=18, H=8) + Linear(8->1) head.
//
// R19b = R19 with the compile fix (h2 = __fp16 ext_vector(2), the actual
// return type of __builtin_amdgcn_cvt_pkrtz). Theory unchanged:
// R18's 32-step-window structure (passed correctness; regressed only
// because 59KB LDS -> 2 blocks/CU -> TWO sequential residency rounds) with
// XG stored as f16 pairs: 40KB -> 20KB, total LDS 38.5KB -> 4 blocks/CU
// retained. Gets R18's rendezvous halving (R12 measured ~510cy/rendezvous)
// WITHOUT the occupancy-round serialization.
//  - producer packs with v_cvt_pkrtz_f16_f32 (1 op, replaces b64 store
//    with b32); consumer unpacks with 2x v_cvt_f32_f16 right next to the
//    1-step-ahead prefetch -> off the recurrence chain.
//  - precision: |xg|~N(0,0.9); f16-rtz err ~2-4e-3 -> through gate slopes
//    and the f<1 c-contraction -> expected absmax ~4-8e-3 < 1.078e-2.
// Everything else byte-identical to R18 (rings, vmcnt(36), swizzle,
// y-flush at k=15/31): Producer iter I: DMA chunks {4I+8..4I+11} (36 ops),
// vmcnt(36) retires {4I+4..4I+7} (issued one iter ~10kcy ago; no stores on
// this wave -> counts exact), produce, lgkm(0), s_barrier. Aring mod-64 /
// Bring mod-8 / XG mod-8 disjointness as derived in R18's header.

namespace {

constexpr int NT = 512;
constexpr int ND = 18;
constexpr float LOG2E = 1.4426950408889634f;

typedef float v2f __attribute__((ext_vector_type(2)));
typedef float v4f __attribute__((ext_vector_type(4)));
typedef __fp16 h2 __attribute__((ext_vector_type(2)));

template <int C>
__device__ __forceinline__ float fdpp(float v) {
    const int i = __float_as_int(v);
    return __int_as_float(__builtin_amdgcn_update_dpp(i, i, C, 0xF, 0xF, true));
}
__device__ __forceinline__ void gload_lds(const void* g, void* l) {
    __builtin_amdgcn_global_load_lds(
        (const __attribute__((address_space(1))) void*)g,
        (__attribute__((address_space(3))) void*)l, 4, 0, 0);
}

__global__ __launch_bounds__(128, 1) void lstm_pc(
    const float* __restrict__ x, const int* __restrict__ lengths,
    const float* __restrict__ W_ih, const float* __restrict__ W_hh,
    const float* __restrict__ b_ih, const float* __restrict__ b_hh,
    const float* __restrict__ W_lin, const float* __restrict__ b_lin,
    float* __restrict__ out)
{
    // Aring: 64 row slots (row r -> slot r&63), [seq][elem0..15].   16KB
    // Bring: 8 chunk bufs, [row-in-chunk][seq][elem16..17].          2KB
    // XG:    8 chunk bufs, [step][gate-pair][seq(+1 pad)] f16x2.    20KB
    __shared__ __align__(16) float    Aring[64][4][16];
    __shared__ __align__(16) float    Bring[8][8][4][2];
    __shared__ __align__(16) unsigned XG[8][8][16][5];

    // Length-balanced swizzle (R14-proven): round-slot q hosts groups
    // {q, 1023-q, 256+q, 767-q} -> per-CU work ~constant.
    const int q_ = (int)blockIdx.x & 255;
    const int r_ = (int)blockIdx.x >> 8;
    const int g  = (r_ == 0) ? q_ : (r_ == 1) ? (1023 - q_)
                 : (r_ == 2) ? (256 + q_) : (767 - q_);

    const int tid  = (int)threadIdx.x;
    const int wav  = tid >> 6;          // 0 = consumer, 1 = producer
    const int w    = tid & 63;
    const int grp  = w >> 4;            // seq within block
    const int l16  = w & 15;
    const int p    = l16 >> 3;          // half: 0 -> {i,g}, 1 -> {f,o}
    const int j    = l16 & 7;           // hidden unit
    const int lenmax = lengths[g * 4];  // sorted desc -> block max
    const int nwin = (lenmax + 31) >> 5;              // 32-step windows
    const int rowA = j + (p ? 8 : 0);   // p0: i, p1: f
    const int rowB = j + (p ? 24 : 16); // p0: g, p1: o

    if (wav == 1) {
        // ============================ PRODUCER ============================
        v2f wxA[9], wxB[9];
        {
            const v2f* ra = (const v2f*)(W_ih + rowA * ND);
            const v2f* rb = (const v2f*)(W_ih + rowB * ND);
#pragma unroll
            for (int k = 0; k < 9; ++k) { wxA[k] = ra[k]; wxB[k] = rb[k]; }
        }
        const float biasA = b_ih[rowA] + b_hh[rowA];
        const float biasB = b_ih[rowB] + b_hh[rowB];

        // DMA source lanes: A-op: seq w>>4, elem w&15 (row uniform).
        // B-op: row w>>3, seq (w>>1)&3, elem 16+(w&1); dest linear = lane.
        const char* xc = (const char*)x;
        const char* pA = xc + (size_t)((((unsigned)(g * 4 + (w >> 4)) * (NT * ND))
                                       + (unsigned)(w & 15)) * 4u);
        const char* pB = xc + (size_t)((((unsigned)(g * 4 + ((w >> 1) & 3)) * (NT * ND))
                                       + 16u + (unsigned)(w & 1)) * 4u);
        const unsigned rB0 = (unsigned)(w >> 3);

        auto dma_chunk = [&](int dd) {            // 9 vmem ops
            const int r0 = dd * 8;
#pragma unroll
            for (int k = 0; k < 8; ++k) {
                const int rr = (r0 + k < NT) ? (r0 + k) : (NT - 1);
                gload_lds(pA + (unsigned)rr * 72u, &Aring[(r0 + k) & 63][0][0]);
            }
            unsigned rb = (unsigned)r0 + rB0;
            rb = (rb < (unsigned)NT) ? rb : (unsigned)(NT - 1);
            gload_lds(pB + rb * 72u, &Bring[dd & 7][0][0][0]);
        };

        // plain compiler-scheduled produce; f16x2 pack at the end
        auto produce_chunk = [&](int cc) {
            const int s0 = (cc * 8) & 63;
            const int bf = cc & 7;
#pragma unroll
            for (int k = 0; k < 8; ++k) {
                const v4f* ap = (const v4f*)&Aring[s0 + k][grp][0];
                const v4f q0 = ap[0], q1 = ap[1], q2 = ap[2], q3 = ap[3];
                const v2f bt = *(const v2f*)&Bring[bf][k][grp][0];
                v2f aA = v2f{biasA, 0.f}, aB = v2f{biasB, 0.f};
                aA = q0.lo * wxA[0] + aA;  aB = q0.lo * wxB[0] + aB;
                aA = q0.hi * wxA[1] + aA;  aB = q0.hi * wxB[1] + aB;
                aA = q1.lo * wxA[2] + aA;  aB = q1.lo * wxB[2] + aB;
                aA = q1.hi * wxA[3] + aA;  aB = q1.hi * wxB[3] + aB;
                aA = q2.lo * wxA[4] + aA;  aB = q2.lo * wxB[4] + aB;
                aA = q2.hi * wxA[5] + aA;  aB = q2.hi * wxB[5] + aB;
                aA = q3.lo * wxA[6] + aA;  aB = q3.lo * wxB[6] + aB;
                aA = q3.hi * wxA[7] + aA;  aB = q3.hi * wxB[7] + aB;
                aA = bt * wxA[8] + aA;     aB = bt * wxB[8] + aB;
                const h2 ph = __builtin_amdgcn_cvt_pkrtz(aA.x + aA.y, aB.x + aB.y);
                XG[bf][k][l16][grp] = __builtin_bit_cast(unsigned, ph);
            }
        };

        // prologue: DMA chunks 0..7 (72 ops); vmcnt(36) -> {0..3} ready
        dma_chunk(0); dma_chunk(1); dma_chunk(2); dma_chunk(3);
        dma_chunk(4); dma_chunk(5); dma_chunk(6); dma_chunk(7);
        asm volatile("s_waitcnt vmcnt(36)" ::: "memory");
        produce_chunk(0); produce_chunk(1); produce_chunk(2); produce_chunk(3);
        asm volatile("s_waitcnt lgkmcnt(0)" ::: "memory");
        __builtin_amdgcn_sched_barrier(0);
        __builtin_amdgcn_s_barrier();
        __builtin_amdgcn_sched_barrier(0);

        for (int I = 0; I < nwin; ++I) {
            dma_chunk(4 * I + 8);
            dma_chunk(4 * I + 9);
            dma_chunk(4 * I + 10);
            dma_chunk(4 * I + 11);
            asm volatile("s_waitcnt vmcnt(36)" ::: "memory");
            produce_chunk(4 * I + 4);
            produce_chunk(4 * I + 5);
            produce_chunk(4 * I + 6);
            produce_chunk(4 * I + 7);
            asm volatile("s_waitcnt lgkmcnt(0)" ::: "memory");
            __builtin_amdgcn_sched_barrier(0);
            __builtin_amdgcn_s_barrier();
            __builtin_amdgcn_sched_barrier(0);
        }
    } else {
        // ============================ CONSUMER ============================
        const int len = lengths[g * 4 + grp];

        // DPP self-calibration: which h-index does row_ror:r deliver here?
        int idx[8];
        idx[0] = j;
        idx[1] = __builtin_amdgcn_update_dpp(0, j, 0x121, 0xF, 0xF, true) & 7;
        idx[2] = __builtin_amdgcn_update_dpp(0, j, 0x122, 0xF, 0xF, true) & 7;
        idx[3] = __builtin_amdgcn_update_dpp(0, j, 0x123, 0xF, 0xF, true) & 7;
        idx[4] = __builtin_amdgcn_update_dpp(0, j, 0x124, 0xF, 0xF, true) & 7;
        idx[5] = __builtin_amdgcn_update_dpp(0, j, 0x125, 0xF, 0xF, true) & 7;
        idx[6] = __builtin_amdgcn_update_dpp(0, j, 0x126, 0xF, 0xF, true) & 7;
        idx[7] = __builtin_amdgcn_update_dpp(0, j, 0x127, 0xF, 0xF, true) & 7;

        v2f whA[4], whB[4], wl2[4];
#pragma unroll
        for (int r = 0; r < 4; ++r) {
            whA[r] = v2f{W_hh[rowA * 8 + idx[2 * r]], W_hh[rowA * 8 + idx[2 * r + 1]]};
            whB[r] = v2f{W_hh[rowB * 8 + idx[2 * r]], W_hh[rowB * 8 + idx[2 * r + 1]]};
            wl2[r] = v2f{W_lin[idx[2 * r]], W_lin[idx[2 * r + 1]]};
        }
        const float bl = b_lin[0];
        // vB exponent scale: p0 computes tanh(g)=2*sigma(2g)-1, p1 sigma(o)
        const float Kp = p ? -LOG2E : -2.0f * LOG2E;

        float* yb = out + (size_t)(g * 4 + grp) * NT;

        v2f hp[4] = {v2f{0.f, 0.f}, v2f{0.f, 0.f}, v2f{0.f, 0.f}, v2f{0.f, 0.f}};
        float c_ = 0.0f, hown = 0.0f;

        __builtin_amdgcn_s_barrier();           // pairs with producer prologue
        __builtin_amdgcn_sched_barrier(0);

        for (int I = 0; I < nwin; ++I) {
            const int t = I * 32;
            // chunk pointers for this window (step stride = 80 u32)
            const unsigned* xgc0 = &XG[(4 * I)     & 7][0][l16][grp];
            const unsigned* xgc1 = &XG[(4 * I + 1) & 7][0][l16][grp];
            const unsigned* xgc2 = &XG[(4 * I + 2) & 7][0][l16][grp];
            const unsigned* xgc3 = &XG[(4 * I + 3) & 7][0][l16][grp];
            float y[16];
            unsigned xgn = xgc0[0]; // first read AFTER barrier (writer last iter)
#pragma unroll
            for (int k = 0; k < 32; ++k) {
                // unpack current (cvt ops run parallel to the h-dot below)
                const h2 ph = __builtin_bit_cast(h2, xgn);
                const float xgA = (float)ph.x;
                const float xgB = (float)ph.y;
                if (k < 31) {
                    const int kn = k + 1;
                    xgn = (kn < 8)  ? xgc0[kn * 80]
                        : (kn < 16) ? xgc1[(kn - 8) * 80]
                        : (kn < 24) ? xgc2[(kn - 16) * 80]
                                    : xgc3[(kn - 24) * 80];
                }

                // recurrent dots
                v2f tA = hp[0] * whA[0];
                tA = hp[1] * whA[1] + tA;
                tA = hp[2] * whA[2] + tA;
                tA = hp[3] * whA[3] + tA;
                v2f tB = hp[0] * whB[0];
                tB = hp[1] * whB[1] + tB;
                tB = hp[2] * whB[2] + tB;
                tB = hp[3] * whB[3] + tB;
                const float aA = (xgA + tA.x) + tA.y;
                const float aB = (xgB + tB.x) + tB.y;

                // activations: vA = sigma(i|f); vB = p0 tanh(g), p1 sigma(o)
                const float vA = __builtin_amdgcn_rcpf(
                    1.0f + __builtin_amdgcn_exp2f(aA * -LOG2E));
                const float sB = __builtin_amdgcn_rcpf(
                    1.0f + __builtin_amdgcn_exp2f(aB * Kp));
                const float vB = p ? sB : fmaf(2.0f, sB, -1.0f);

                // half exchange via ror:8; unmasked cell update
                const float send1 = p ? vA : (vA * vB);
                const float ex1 = fdpp<0x128>(send1);
                const float f_ = p ? send1 : ex1;
                const float ig_ = p ? ex1 : send1;
                c_ = fmaf(f_, c_, ig_);
                const float tc = fmaf(-2.0f, __builtin_amdgcn_rcpf(
                    1.0f + __builtin_amdgcn_exp2f(c_ * (2.0f * LOG2E))), 1.0f);
                const float ex2 = fdpp<0x128>(vB);
                const float o_ = p ? vB : ex2;
                hown = o_ * tc;

                // h rotations -> pairs
                const float h1 = fdpp<0x121>(hown);
                const float h2r = fdpp<0x122>(hown);
                const float h3 = fdpp<0x123>(hown);
                const float h4 = fdpp<0x124>(hown);
                const float h5 = fdpp<0x125>(hown);
                const float h6 = fdpp<0x126>(hown);
                const float h7 = fdpp<0x127>(hown);
                hp[0] = v2f{hown, h1}; hp[1] = v2f{h2r, h3};
                hp[2] = v2f{h4, h5};   hp[3] = v2f{h6, h7};

                // linear head (off the critical chain)
                v2f ya = hp[0] * wl2[0];
                ya = hp[1] * wl2[1] + ya;
                ya = hp[2] * wl2[2] + ya;
                ya = hp[3] * wl2[3] + ya;
                y[k & 15] = (ya.x + ya.y) + bl;

                // flush y in 16-step groups (caps VGPR use)
                if (k == 15 || k == 31) {
                    const int tb = t + (k & 16);
                    if (l16 == 0) {
                        if (tb + 15 < len) {
                            *(v4f*)(yb + tb)      = v4f{y[0],  y[1],  y[2],  y[3]};
                            *(v4f*)(yb + tb + 4)  = v4f{y[4],  y[5],  y[6],  y[7]};
                            *(v4f*)(yb + tb + 8)  = v4f{y[8],  y[9],  y[10], y[11]};
                            *(v4f*)(yb + tb + 12) = v4f{y[12], y[13], y[14], y[15]};
                        } else {
#pragma unroll
                            for (int kk = 0; kk < 16; ++kk)
                                if (tb + kk < len) yb[tb + kk] = y[kk];
                        }
                    }
                }
            }

            __builtin_amdgcn_sched_barrier(0);
            __builtin_amdgcn_s_barrier();
            __builtin_amdgcn_sched_barrier(0);
        }
    }
}

} // namespace

extern "C" void kernel_launch(void* const* d_in, const int* in_sizes, int n_in,
                              void* d_out, int out_size, void* d_ws, size_t ws_size,
                              hipStream_t stream) {
    const float* x     = (const float*)d_in[0];
    const int*   lens  = (const int*)d_in[1];
    const float* W_ih  = (const float*)d_in[2];
    const float* W_hh  = (const float*)d_in[3];
    const float* b_ih  = (const float*)d_in[4];
    const float* b_hh  = (const float*)d_in[5];
    const float* W_lin = (const float*)d_in[6];
    const float* b_lin = (const float*)d_in[7];
    float* out = (float*)d_out;

    // zero the padded region (kernel only writes t < len)
    hipMemsetAsync(out, 0, (size_t)4096 * NT * sizeof(float), stream);

    lstm_pc<<<1024, 128, 0, stream>>>(x, lens, W_ih, W_hh, b_ih, b_hh,
                                      W_lin, b_lin, out);
}

// Round 21
// 75.966 us; speedup vs baseline: 1.3479x; 1.0606x over previous
//
#include <hip/hip_runtime.h>

// Packed-sequence LSTM (B=4096, T=512, D=18, H=8) + Linear(8->1) head.
//
// R20 = R14 VERBATIM (best measured: 75.9us). Terminal-candidate revert.
//
// Why this is (near) the floor for this structure [R7..R19 evidence]:
//   wall = total VALU issue / SIMDs + ~20% sync: per-CU per-window issue
//   = 8 waves x 40% x 5700cy ~= 4560cy/SIMD of the 5700cy window (80%
//   SIMD-issue occupancy). Confirmations: R19b +7% instr -> +6% wall;
//   R8/R9 producer slowdowns -> proportional wall growth. Attempts to cut
//   instruction count genuinely all failed: R11/R13 inline-asm pkfma adds
//   operand copies (VALUBusy unchanged); R17 __builtin_elementwise_fma =
//   identical codegen (VGPR/VALUBusy unchanged); R19 f16-XG added cvt work.
//   Structure alternatives measured worse: R16 1-wave/SIMD w/ shfl chain
//   (105us: ds_bpermute on serial chain), R18 2-blocks/CU (102us: two
//   residency rounds), R15 head offload (77.5us: LDS roundtrip + conflicts).
//   Wins that stand: producer/consumer wave split (R7), 16-step windows
//   (R12), length-balanced CU-load swizzle (R14).
//
// Structure: block = 2 waves, 4 seqs. Producer (wave 1): LDS-DMA A/B rings
// (R7-proven lane maps), counted vmcnt (18 ops/window; vmcnt(18) retires
// the window issued one iter ago; no stores on this wave -> counts exact),
// computes xg[t] = W_ih.x_t + bias into a 4-chunk XG ring, lgkm(0),
// s_barrier. Consumer (wave 0): serial LSTM, 1 ds_read_b64/step (prefetch
// 1 ahead; first read of each window AFTER the barrier), DPP-only
// cross-lane (ror:8 gate exchange; ror:1..7 h-rotation with rotation-
// ordered weights via runtime DPP self-calibration), batched y stores,
// s_barrier. Raw s_barrier only (never __syncthreads - drains vmcnt).

namespace {

constexpr int NT = 512;
constexpr int ND = 18;
constexpr float LOG2E = 1.4426950408889634f;

typedef float v2f __attribute__((ext_vector_type(2)));
typedef float v4f __attribute__((ext_vector_type(4)));

template <int C>
__device__ __forceinline__ float fdpp(float v) {
    const int i = __float_as_int(v);
    return __int_as_float(__builtin_amdgcn_update_dpp(i, i, C, 0xF, 0xF, true));
}
__device__ __forceinline__ void gload_lds(const void* g, void* l) {
    __builtin_amdgcn_global_load_lds(
        (const __attribute__((address_space(1))) void*)g,
        (__attribute__((address_space(3))) void*)l, 4, 0, 0);
}

__global__ __launch_bounds__(128, 1) void lstm_pc(
    const float* __restrict__ x, const int* __restrict__ lengths,
    const float* __restrict__ W_ih, const float* __restrict__ W_hh,
    const float* __restrict__ b_ih, const float* __restrict__ b_hh,
    const float* __restrict__ W_lin, const float* __restrict__ b_lin,
    float* __restrict__ out)
{
    // A ring: 32 row slots (row r -> slot r&31), [seq][elem0..15].
    // B ring: 4 chunk blocks, [row-in-chunk][seq][elem16..17].
    // XG ring: 4 chunk buffers, [t-in-chunk][gate-pair][seq(+1 pad)] of v2f.
    __shared__ __align__(16) float Aring[32][4][16];
    __shared__ __align__(16) float Bring[4][8][4][2];
    __shared__ __align__(16) v2f   XG[4][8][16][5];

    // Length-balanced swizzle: CU hosting round-slot q gets groups
    // {q, 1023-q, 256+q, 767-q} -> per-CU work ~constant (~1024 step-units).
    const int q_ = (int)blockIdx.x & 255;
    const int r_ = (int)blockIdx.x >> 8;
    const int g  = (r_ == 0) ? q_ : (r_ == 1) ? (1023 - q_)
                 : (r_ == 2) ? (256 + q_) : (767 - q_);

    const int tid  = (int)threadIdx.x;
    const int wav  = tid >> 6;          // 0 = consumer, 1 = producer
    const int w    = tid & 63;
    const int grp  = w >> 4;            // seq within block
    const int l16  = w & 15;
    const int p    = l16 >> 3;          // half: 0 -> {i,g}, 1 -> {f,o}
    const int j    = l16 & 7;           // hidden unit
    const int lenmax = lengths[g * 4];  // sorted desc -> block max
    const int nwin = (lenmax + 15) >> 4;              // 16-step windows
    const int rowA = j + (p ? 8 : 0);   // p0: i, p1: f
    const int rowB = j + (p ? 24 : 16); // p0: g, p1: o

    if (wav == 1) {
        // ============================ PRODUCER ============================
        v2f wxA[9], wxB[9];
        {
            const v2f* ra = (const v2f*)(W_ih + rowA * ND);
            const v2f* rb = (const v2f*)(W_ih + rowB * ND);
#pragma unroll
            for (int k = 0; k < 9; ++k) { wxA[k] = ra[k]; wxB[k] = rb[k]; }
        }
        const float biasA = b_ih[rowA] + b_hh[rowA];
        const float biasB = b_ih[rowB] + b_hh[rowB];

        // DMA source lanes: A-op: seq w>>4, elem w&15 (row uniform).
        // B-op: row w>>3, seq (w>>1)&3, elem 16+(w&1); dest linear = lane.
        const char* xc = (const char*)x;
        const char* pA = xc + (size_t)((((unsigned)(g * 4 + (w >> 4)) * (NT * ND))
                                       + (unsigned)(w & 15)) * 4u);
        const char* pB = xc + (size_t)((((unsigned)(g * 4 + ((w >> 1) & 3)) * (NT * ND))
                                       + 16u + (unsigned)(w & 1)) * 4u);
        const unsigned rB0 = (unsigned)(w >> 3);

        auto dma_chunk = [&](int dd) {
            const int r0 = dd * 8;
#pragma unroll
            for (int k = 0; k < 8; ++k) {
                const int rr = (r0 + k < NT) ? (r0 + k) : (NT - 1);
                gload_lds(pA + (unsigned)rr * 72u, &Aring[(r0 + k) & 31][0][0]);
            }
            unsigned rb = (unsigned)r0 + rB0;
            rb = (rb < (unsigned)NT) ? rb : (unsigned)(NT - 1);
            gload_lds(pB + rb * 72u, &Bring[dd & 3][0][0][0]);
        };

        // plain compiler-scheduled produce (R9/R11/R13/R17: no hand-tuning)
        auto produce_chunk = [&](int cc) {
            const int s0 = (cc * 8) & 31;
            const int bf = cc & 3;
#pragma unroll
            for (int k = 0; k < 8; ++k) {
                const v4f* ap = (const v4f*)&Aring[s0 + k][grp][0];
                const v4f q0 = ap[0], q1 = ap[1], q2 = ap[2], q3 = ap[3];
                const v2f bt = *(const v2f*)&Bring[bf][k][grp][0];
                v2f aA = v2f{biasA, 0.f}, aB = v2f{biasB, 0.f};
                aA = q0.lo * wxA[0] + aA;  aB = q0.lo * wxB[0] + aB;
                aA = q0.hi * wxA[1] + aA;  aB = q0.hi * wxB[1] + aB;
                aA = q1.lo * wxA[2] + aA;  aB = q1.lo * wxB[2] + aB;
                aA = q1.hi * wxA[3] + aA;  aB = q1.hi * wxB[3] + aB;
                aA = q2.lo * wxA[4] + aA;  aB = q2.lo * wxB[4] + aB;
                aA = q2.hi * wxA[5] + aA;  aB = q2.hi * wxB[5] + aB;
                aA = q3.lo * wxA[6] + aA;  aB = q3.lo * wxB[6] + aB;
                aA = q3.hi * wxA[7] + aA;  aB = q3.hi * wxB[7] + aB;
                aA = bt * wxA[8] + aA;     aB = bt * wxB[8] + aB;
                XG[bf][k][l16][grp] = v2f{aA.x + aA.y, aB.x + aB.y};
            }
        };

        // prologue: DMA chunks 0..3 (36 ops); {0,1} ready after vmcnt(18)
        dma_chunk(0); dma_chunk(1); dma_chunk(2); dma_chunk(3);
        asm volatile("s_waitcnt vmcnt(18)" ::: "memory");
        produce_chunk(0);
        produce_chunk(1);
        asm volatile("s_waitcnt lgkmcnt(0)" ::: "memory");
        __builtin_amdgcn_sched_barrier(0);
        __builtin_amdgcn_s_barrier();
        __builtin_amdgcn_sched_barrier(0);

        for (int I = 0; I < nwin; ++I) {
            dma_chunk(2 * I + 4);
            dma_chunk(2 * I + 5);
            asm volatile("s_waitcnt vmcnt(18)" ::: "memory");
            produce_chunk(2 * I + 2);
            produce_chunk(2 * I + 3);
            asm volatile("s_waitcnt lgkmcnt(0)" ::: "memory");
            __builtin_amdgcn_sched_barrier(0);
            __builtin_amdgcn_s_barrier();
            __builtin_amdgcn_sched_barrier(0);
        }
    } else {
        // ============================ CONSUMER ============================
        const int len = lengths[g * 4 + grp];

        // DPP self-calibration: which h-index does row_ror:r deliver here?
        int idx[8];
        idx[0] = j;
        idx[1] = __builtin_amdgcn_update_dpp(0, j, 0x121, 0xF, 0xF, true) & 7;
        idx[2] = __builtin_amdgcn_update_dpp(0, j, 0x122, 0xF, 0xF, true) & 7;
        idx[3] = __builtin_amdgcn_update_dpp(0, j, 0x123, 0xF, 0xF, true) & 7;
        idx[4] = __builtin_amdgcn_update_dpp(0, j, 0x124, 0xF, 0xF, true) & 7;
        idx[5] = __builtin_amdgcn_update_dpp(0, j, 0x125, 0xF, 0xF, true) & 7;
        idx[6] = __builtin_amdgcn_update_dpp(0, j, 0x126, 0xF, 0xF, true) & 7;
        idx[7] = __builtin_amdgcn_update_dpp(0, j, 0x127, 0xF, 0xF, true) & 7;

        v2f whA[4], whB[4], wl2[4];
#pragma unroll
        for (int r = 0; r < 4; ++r) {
            whA[r] = v2f{W_hh[rowA * 8 + idx[2 * r]], W_hh[rowA * 8 + idx[2 * r + 1]]};
            whB[r] = v2f{W_hh[rowB * 8 + idx[2 * r]], W_hh[rowB * 8 + idx[2 * r + 1]]};
            wl2[r] = v2f{W_lin[idx[2 * r]], W_lin[idx[2 * r + 1]]};
        }
        const float bl = b_lin[0];
        // vB exponent scale: p0 computes tanh(g)=2*sigma(2g)-1, p1 sigma(o)
        const float Kp = p ? -LOG2E : -2.0f * LOG2E;

        float* yb = out + (size_t)(g * 4 + grp) * NT;

        v2f hp[4] = {v2f{0.f, 0.f}, v2f{0.f, 0.f}, v2f{0.f, 0.f}, v2f{0.f, 0.f}};
        float c_ = 0.0f, hown = 0.0f;

        __builtin_amdgcn_s_barrier();           // pairs with producer prologue
        __builtin_amdgcn_sched_barrier(0);

        for (int I = 0; I < nwin; ++I) {
            const int t = I * 16;
            const v2f* xg0 = &XG[(2 * I) & 3][0][l16][grp];      // step stride 80 v2f
            const v2f* xg1 = &XG[(2 * I + 1) & 3][0][l16][grp];
            float y[16];
            v2f xgn = xg0[0];   // first read AFTER barrier (writer was last window)
#pragma unroll
            for (int k = 0; k < 16; ++k) {
                const v2f xgc = xgn;
                if (k < 15) xgn = (k + 1 < 8) ? xg0[(k + 1) * 80] : xg1[(k + 1 - 8) * 80];

                // recurrent dots
                v2f tA = hp[0] * whA[0];
                tA = hp[1] * whA[1] + tA;
                tA = hp[2] * whA[2] + tA;
                tA = hp[3] * whA[3] + tA;
                v2f tB = hp[0] * whB[0];
                tB = hp[1] * whB[1] + tB;
                tB = hp[2] * whB[2] + tB;
                tB = hp[3] * whB[3] + tB;
                const float aA = (xgc.x + tA.x) + tA.y;
                const float aB = (xgc.y + tB.x) + tB.y;

                // activations: vA = sigma(i|f); vB = p0 tanh(g), p1 sigma(o)
                const float vA = __builtin_amdgcn_rcpf(
                    1.0f + __builtin_amdgcn_exp2f(aA * -LOG2E));
                const float sB = __builtin_amdgcn_rcpf(
                    1.0f + __builtin_amdgcn_exp2f(aB * Kp));
                const float vB = p ? sB : fmaf(2.0f, sB, -1.0f);

                // half exchange via ror:8; unmasked cell update
                const float send1 = p ? vA : (vA * vB);
                const float ex1 = fdpp<0x128>(send1);
                const float f_ = p ? send1 : ex1;
                const float ig_ = p ? ex1 : send1;
                c_ = fmaf(f_, c_, ig_);
                const float tc = fmaf(-2.0f, __builtin_amdgcn_rcpf(
                    1.0f + __builtin_amdgcn_exp2f(c_ * (2.0f * LOG2E))), 1.0f);
                const float ex2 = fdpp<0x128>(vB);
                const float o_ = p ? vB : ex2;
                hown = o_ * tc;

                // h rotations -> pairs
                const float h1 = fdpp<0x121>(hown);
                const float h2 = fdpp<0x122>(hown);
                const float h3 = fdpp<0x123>(hown);
                const float h4 = fdpp<0x124>(hown);
                const float h5 = fdpp<0x125>(hown);
                const float h6 = fdpp<0x126>(hown);
                const float h7 = fdpp<0x127>(hown);
                hp[0] = v2f{hown, h1}; hp[1] = v2f{h2, h3};
                hp[2] = v2f{h4, h5};   hp[3] = v2f{h6, h7};

                // linear head (off the critical chain)
                v2f ya = hp[0] * wl2[0];
                ya = hp[1] * wl2[1] + ya;
                ya = hp[2] * wl2[2] + ya;
                ya = hp[3] * wl2[3] + ya;
                y[k] = (ya.x + ya.y) + bl;
            }

            if (l16 == 0) {
                if (t + 15 < len) {
                    *(v4f*)(yb + t)      = v4f{y[0],  y[1],  y[2],  y[3]};
                    *(v4f*)(yb + t + 4)  = v4f{y[4],  y[5],  y[6],  y[7]};
                    *(v4f*)(yb + t + 8)  = v4f{y[8],  y[9],  y[10], y[11]};
                    *(v4f*)(yb + t + 12) = v4f{y[12], y[13], y[14], y[15]};
                } else {
#pragma unroll
                    for (int k = 0; k < 16; ++k)
                        if (t + k < len) yb[t + k] = y[k];
                }
            }
            __builtin_amdgcn_sched_barrier(0);
            __builtin_amdgcn_s_barrier();
            __builtin_amdgcn_sched_barrier(0);
        }
    }
}

} // namespace

extern "C" void kernel_launch(void* const* d_in, const int* in_sizes, int n_in,
                              void* d_out, int out_size, void* d_ws, size_t ws_size,
                              hipStream_t stream) {
    const float* x     = (const float*)d_in[0];
    const int*   lens  = (const int*)d_in[1];
    const float* W_ih  = (const float*)d_in[2];
    const float* W_hh  = (const float*)d_in[3];
    const float* b_ih  = (const float*)d_in[4];
    const float* b_hh  = (const float*)d_in[5];
    const float* W_lin = (const float*)d_in[6];
    const float* b_lin = (const float*)d_in[7];
    float* out = (float*)d_out;

    // zero the padded region (kernel only writes t < len)
    hipMemsetAsync(out, 0, (size_t)4096 * NT * sizeof(float), stream);

    lstm_pc<<<1024, 128, 0, stream>>>(x, lens, W_ih, W_hh, b_ih, b_hh,
                                      W_lin, b_lin, out);
}